// Round 1
// 435.020 us; speedup vs baseline: 1.0726x; 1.0726x over previous
//
#include <hip/hip_runtime.h>
#include <hip/hip_bf16.h>
#include <math.h>

// Problem constants
#define BATCH 512
#define NSEG  64
#define HID   1024
#define ATT   128

typedef __attribute__((ext_vector_type(8))) __bf16 bf16x8;
typedef __attribute__((ext_vector_type(4))) __bf16 bf16x4;
typedef __attribute__((ext_vector_type(4))) float  f32x4;

// ---------------------------------------------------------------------------
// conv1 weight pre-convert: w[co][ci][kh][kw] (8,3,5,5) fp32 ->
// wt[k8][m16][j8] bf16 with k = tap*4 + ci (ci padded to 4), K=100 pad 128.
// Zeros at ci=3, tap>=25, m>=8  => A-side zero kills all padding in MFMA.
// ---------------------------------------------------------------------------
__global__ void wconv1_k(const float* __restrict__ w, __bf16* __restrict__ wt) {
    int t = blockIdx.x * 256 + threadIdx.x;   // n = 16*16*8 = 2048
    if (t >= 2048) return;
    int j = t & 7, m = (t >> 3) & 15, k8 = t >> 7;
    int k = k8 * 8 + j, tap = k >> 2, ci = k & 3;
    float v = 0.f;
    if (m < 8 && ci < 3 && tap < 25) v = w[(m * 3 + ci) * 25 + tap];
    wt[t] = (__bf16)v;
}

// ---------------------------------------------------------------------------
// conv1 via MFMA, 2D tile + zero-padded halo (round 9 rewrite).
// Block = 4 output rows x 128 cols of one image. LDS tile xs[8][132][4ci]
// has zeros physically staged at all out-of-image / out-of-row positions,
// so the MFMA inner loop needs NO masking: per tap it is just
// 2 x ds_read_b64 + mfma at a constant byte shift.  Fused pool+relu ->
// NHWC8 bf16 for conv2 (layout identical to previous version).
// ---------------------------------------------------------------------------
__global__ __launch_bounds__(256) void conv1_mfma_k(
    const float* __restrict__ in, const __bf16* __restrict__ Wt,
    const float* __restrict__ bias, __bf16* __restrict__ out) {
    constexpr int W  = 128;
    constexpr int R  = 4;                  // output rows per block
    constexpr int RP = R + 4;              // padded rows (halo 2 each side)
    constexpr int WP = W + 4;              // padded cols
    constexpr int CSTR = R * W + 4;        // 516 f32: 516%32=4 -> 2-way (free)

    __shared__ __align__(16) __bf16 xs[RP * WP * 4];   // 8*132*4*2B = 8448 B
    __shared__ float cs[8 * CSTR];                     // 16512 B

    const int tid = threadIdx.x;
    const int b   = blockIdx.x >> 5;            // 32 row-blocks per image
    const int y0  = (blockIdx.x & 31) * R;
    const float* inb = in + (size_t)b * 3 * 16384;

    // ---- zero the left/right halo columns (-2,-1,130,131) ----
    if (tid < RP * 4) {
        int r = tid >> 2, s = tid & 3;
        int c = (s < 2) ? s : (128 + s);        // 0,1,130,131
        *(bf16x4*)(xs + (r * WP + c) * 4) = (bf16x4){};
    }
    // ---- stage rows y0-2 .. y0+R+1 as NHWC4 bf16, zeros out-of-image ----
    {
        int r  = tid >> 5;                      // 0..7 padded row
        int g  = tid & 31;                      // col group, 4 cols
        int gy = y0 + r - 2;
        int c0 = g * 4;
        bf16x8 lo = {}, hi = {};
        if ((unsigned)gy < 128u) {
            const float* p = inb + (size_t)gy * 128 + c0;
            float4 a = *(const float4*)(p);
            float4 q = *(const float4*)(p + 16384);
            float4 c = *(const float4*)(p + 32768);
            lo[0] = (__bf16)a.x; lo[1] = (__bf16)q.x; lo[2] = (__bf16)c.x;
            lo[4] = (__bf16)a.y; lo[5] = (__bf16)q.y; lo[6] = (__bf16)c.y;
            hi[0] = (__bf16)a.z; hi[1] = (__bf16)q.z; hi[2] = (__bf16)c.z;
            hi[4] = (__bf16)a.w; hi[5] = (__bf16)q.w; hi[6] = (__bf16)c.w;
        }
        *(bf16x8*)(xs + (r * WP + c0 + 2) * 4)     = lo;
        *(bf16x8*)(xs + (r * WP + c0 + 2) * 4 + 8) = hi;
    }
    __syncthreads();

    const int lane = tid & 63, wave = tid >> 6;
    const int quad = lane >> 4, l15 = lane & 15;
    constexpr int F = 8;                        // col groups per row (= per wave)

    int pbase[F];                               // byte offsets into xs
    f32x4 acc[F];
#pragma unroll
    for (int f = 0; f < F; ++f) {
        pbase[f] = ((wave + 2) * WP + f * 16 + l15 + 2) * 8;
        acc[f] = f32x4{0.f, 0.f, 0.f, 0.f};
    }
    const char* xsb = (const char*)xs;

#pragma unroll
    for (int kt = 0; kt < 4; ++kt) {
        int k8 = kt * 4 + quad;
        int tap0 = k8 * 2, tap1 = tap0 + 1;
        int t0 = tap0 < 25 ? tap0 : 0;          // clamp: A-side weights are 0 there
        int t1 = tap1 < 25 ? tap1 : 0;
        int s0 = ((t0 / 5 - 2) * WP + (t0 % 5 - 2)) * 8;
        int s1 = ((t1 / 5 - 2) * WP + (t1 % 5 - 2)) * 8;
        bf16x8 av = *(const bf16x8*)(Wt + ((size_t)k8 * 16 + l15) * 8);
#pragma unroll
        for (int f = 0; f < F; ++f) {
            bf16x4 b0 = *(const bf16x4*)(xsb + pbase[f] + s0);
            bf16x4 b1 = *(const bf16x4*)(xsb + pbase[f] + s1);
            bf16x8 bv = __builtin_shufflevector(b0, b1, 0, 1, 2, 3, 4, 5, 6, 7);
            acc[f] = __builtin_amdgcn_mfma_f32_16x16x32_bf16(av, bv, acc[f], 0, 0, 0);
        }
    }

    // ---- acc -> LDS (C/D: col=l15=pixel, row=quad*4+r=co) ----
#pragma unroll
    for (int f = 0; f < F; ++f) {
        int pl = wave * 128 + f * 16 + l15;
#pragma unroll
        for (int r = 0; r < 4; ++r) {
            int m = quad * 4 + r;
            if (m < 8) cs[m * CSTR + pl] = acc[f][r];
        }
    }
    __syncthreads();

    // ---- pool 2x2 + bias + relu -> NHWC8 bf16; 128 opos x (2 x 4co) ----
    {
        int oi  = tid >> 1;                     // 0..127 pooled positions
        int cog = (tid & 1) * 4;                // 0 or 4
        int oy  = oi >> 6, ox = oi & 63;
        int pl0 = oy * 2 * 128 + ox * 2;
        float4 b4 = *(const float4*)(bias + cog);
        bf16x4 ov;
#pragma unroll
        for (int i = 0; i < 4; ++i) {
            int cr = cog + i;
            float v0 = cs[cr * CSTR + pl0],       v1 = cs[cr * CSTR + pl0 + 1];
            float v2 = cs[cr * CSTR + pl0 + 128], v3 = cs[cr * CSTR + pl0 + 129];
            float m = fmaxf(fmaxf(v0, v1), fmaxf(v2, v3)) + ((const float*)&b4)[i];
            ov[i] = (__bf16)fmaxf(m, 0.f);
        }
        size_t ob = ((size_t)b * 4096 + (size_t)(y0 / 2 + oy) * 64 + ox) * 8 + cog;
        *(bf16x4*)(out + ob) = ov;
    }
}

// ---------------------------------------------------------------------------
// Conv weight pre-convert: w[co][ci][kh][kw] fp32 -> wt[k/8][co][k%8] bf16,
// k = (kh*5+kw)*Ci + ci  (A-frag: lane m=lane&15 reads 16B = A[co][k8*8..+7]).
// ---------------------------------------------------------------------------
template<int Ci, int Co>
__global__ void wconv_k(const float* __restrict__ w, __bf16* __restrict__ wt) {
    const int n = 25 * Ci * Co;
    int t = blockIdx.x * 256 + threadIdx.x;
    if (t >= n) return;
    int j  = t & 7;
    int t2 = t >> 3;
    int co = t2 % Co;
    int k8 = t2 / Co;
    int k  = k8 * 8 + j;
    int tap = k / Ci, ci = k % Ci;
    int kh = tap / 5, kw = tap % 5;
    wt[t] = (__bf16)w[((co * Ci + ci) * 25) + kh * 5 + kw];
}

// ---------------------------------------------------------------------------
// FC weight pre-convert: fcw[o][k] fp32 (o<1024, k<2048) -> wt[k8][o][j] bf16.
// ---------------------------------------------------------------------------
__global__ void wfc_k(const float* __restrict__ w, __bf16* __restrict__ wt) {
    int t = blockIdx.x * 256 + threadIdx.x;   // n = 1024*2048 = 2,097,152
    int j  = t & 7;
    int t2 = t >> 3;
    int o  = t2 & 1023;
    int k8 = t2 >> 10;
    wt[t] = (__bf16)w[(size_t)o * 2048 + k8 * 8 + j];
}

// ---------------------------------------------------------------------------
// MFMA implicit-GEMM conv5x5(same) + bias + maxpool2 + relu.
// Hardened form verified rounds 6-8.  OUTMODE: 0 = NHWC bf16, 1 = flat bf16
// [b][co*16+oy*4+ox] (conv5 -> FC input, matches NCHW flatten order).
// ---------------------------------------------------------------------------
template<int Ci, int Co, int H, int OUTMODE>
__global__ __launch_bounds__(256) void conv_mfma_k(
    const __bf16* __restrict__ X, const __bf16* __restrict__ Wt,
    const float* __restrict__ bias, void* __restrict__ outp) {
    constexpr int W = H, NPIX = H * W, NTOT = BATCH * NPIX;
    constexpr int HALO = 2 * W + 2, SPAN = 256 + 2 * HALO, STR = Ci + 8;
    constexpr int K = 25 * Ci, KT = (K + 31) / 32;
    constexpr int LOGW = (W == 64 ? 6 : (W == 32 ? 5 : (W == 16 ? 4 : 3)));

    __shared__ __align__(16) __bf16 xs[SPAN * STR];
    __shared__ float cs[16 * 256];

    const int tid  = threadIdx.x;
    const int pos0 = blockIdx.x * 256;
    const int co0  = blockIdx.y * 16;

    constexpr int C8 = Ci / 8;
    for (int i = tid; i < SPAN * C8; i += 256) {
        int p   = i / C8;
        int cio = (i % C8) * 8;
        int gp  = pos0 - HALO + p;
        gp = gp < 0 ? 0 : (gp > NTOT - 1 ? NTOT - 1 : gp);
        *(bf16x8*)(xs + p * STR + cio) = *(const bf16x8*)(X + (size_t)gp * Ci + cio);
    }
    __syncthreads();

    const int lane = tid & 63, wave = tid >> 6;
    const int quad = lane >> 4, l15 = lane & 15;

    int px[4], py[4], pbase[4];
    f32x4 acc[4];
#pragma unroll
    for (int f = 0; f < 4; ++f) {
        int pl = wave * 64 + f * 16 + l15;
        int p  = pos0 + pl;
        px[f] = p & (W - 1);
        py[f] = (p >> LOGW) & (H - 1);
        pbase[f] = (pl + HALO) * STR;
        acc[f] = f32x4{0.f, 0.f, 0.f, 0.f};
    }
    const bf16x8 BZ = {};

    for (int kt = 0; kt < KT; ++kt) {
        int k8 = kt * 4 + quad;
        int kk = k8 * 8;
        bool kok = kk < K;
        int kkc  = kok ? kk : 0;
        int tap  = kkc / Ci;
        int cib  = kkc % Ci;
        int dy   = tap / 5 - 2;
        int dx   = tap % 5 - 2;
        int shift = dy * W + dx;
        bf16x8 av = *(const bf16x8*)(Wt + ((size_t)(kok ? k8 : 0) * Co + co0 + l15) * 8);
#pragma unroll
        for (int f = 0; f < 4; ++f) {
            bf16x8 bv = *(const bf16x8*)(xs + pbase[f] + shift * STR + cib);
            bool valid = kok && ((unsigned)(px[f] + dx) < (unsigned)W)
                             && ((unsigned)(py[f] + dy) < (unsigned)H);
            if (!valid) bv = BZ;
            acc[f] = __builtin_amdgcn_mfma_f32_16x16x32_bf16(av, bv, acc[f], 0, 0, 0);
        }
    }

#pragma unroll
    for (int f = 0; f < 4; ++f) {
        int pl = wave * 64 + f * 16 + l15;
#pragma unroll
        for (int r = 0; r < 4; ++r) cs[(quad * 4 + r) * 256 + pl] = acc[f][r];
    }
    __syncthreads();

    {
        int opos = tid >> 2;
        int cog  = (tid & 3) * 4;
        int ocol = opos & (W / 2 - 1);
        int orow = opos >> (LOGW - 1);
        int pl0  = (orow * 2) * W + ocol * 2;
        int p    = pos0 + pl0;
        int b    = p >> (2 * LOGW);
        int yy   = (p >> LOGW) & (H - 1);
        int xx   = p & (W - 1);
        int oy = yy >> 1, ox = xx >> 1;
#pragma unroll
        for (int i = 0; i < 4; ++i) {
            int cr = cog + i;
            float v0 = cs[cr * 256 + pl0],     v1 = cs[cr * 256 + pl0 + 1];
            float v2 = cs[cr * 256 + pl0 + W], v3 = cs[cr * 256 + pl0 + W + 1];
            float m = fmaxf(fmaxf(v0, v1), fmaxf(v2, v3)) + bias[co0 + cr];
            m = fmaxf(m, 0.f);
            if (OUTMODE == 1) {
                ((__bf16*)outp)[(size_t)b * 2048 + (co0 + cr) * 16 + oy * 4 + ox] = (__bf16)m;
            } else {
                ((__bf16*)outp)[((size_t)((b * (H / 2) + oy) * (W / 2)) + ox) * Co + co0 + cr] = (__bf16)m;
            }
        }
    }
}

// ---------------------------------------------------------------------------
// FC via MFMA (verified round 8).
// ---------------------------------------------------------------------------
__global__ __launch_bounds__(256) void fc_mfma_k(
    const __bf16* __restrict__ Xb, const __bf16* __restrict__ Wfc,
    const float* __restrict__ bias, float* __restrict__ emb) {
    const int tid  = threadIdx.x;
    const int lane = tid & 63, wave = tid >> 6;
    const int quad = lane >> 4, l15 = lane & 15;
    const int n0   = blockIdx.x * 128;
    const int co0  = blockIdx.y * 16;

    int n[2];
    f32x4 acc[2];
#pragma unroll
    for (int f = 0; f < 2; ++f) {
        n[f] = n0 + wave * 32 + f * 16 + l15;
        acc[f] = f32x4{0.f, 0.f, 0.f, 0.f};
    }

#pragma unroll 4
    for (int kt = 0; kt < 64; ++kt) {
        int k8 = kt * 4 + quad;
        bf16x8 av = *(const bf16x8*)(Wfc + ((size_t)k8 * 1024 + co0 + l15) * 8);
#pragma unroll
        for (int f = 0; f < 2; ++f) {
            bf16x8 bv = *(const bf16x8*)(Xb + (size_t)n[f] * 2048 + k8 * 8);
            acc[f] = __builtin_amdgcn_mfma_f32_16x16x32_bf16(av, bv, acc[f], 0, 0, 0);
        }
    }

    float4 b4 = *(const float4*)(bias + co0 + quad * 4);
#pragma unroll
    for (int f = 0; f < 2; ++f) {
        f32x4 v = acc[f];
        v[0] += b4.x; v[1] += b4.y; v[2] += b4.z; v[3] += b4.w;
        *(f32x4*)(emb + (size_t)n[f] * 1024 + co0 + quad * 4) = v;
    }
}

// ---------------------------------------------------------------------------
// Attention
// ---------------------------------------------------------------------------
__global__ __launch_bounds__(128) void attention_k(
    const float* __restrict__ emb, const float* __restrict__ w1,
    const float* __restrict__ b1, const float* __restrict__ w2,
    const float* __restrict__ b2, float* __restrict__ logits) {
    const int b = blockIdx.x;
    const int j = threadIdx.x;
    __shared__ float es[HID];
    for (int k = j; k < HID; k += 128) es[k] = emb[(size_t)b * HID + k];
    __syncthreads();

    float s = b1[j];
    const float* wr = w1 + (size_t)j * HID;
    for (int k = 0; k < HID; k += 4) {
        float4 wv = *(const float4*)(wr + k);
        float4 ev = *(const float4*)(es + k);
        s += wv.x * ev.x + wv.y * ev.y + wv.z * ev.z + wv.w * ev.w;
    }
    float v = tanhf(s) * w2[j];
#pragma unroll
    for (int off = 32; off > 0; off >>= 1) v += __shfl_down(v, off);
    __shared__ float wsum[2];
    if ((j & 63) == 0) wsum[j >> 6] = v;
    __syncthreads();
    if (j == 0) logits[b] = wsum[0] + wsum[1] + b2[0];
}

// ---------------------------------------------------------------------------
// Segment softmax + aggregation + classifier
// ---------------------------------------------------------------------------
__global__ __launch_bounds__(256) void segment_k(
    const float* __restrict__ emb, const float* __restrict__ logits,
    const int* __restrict__ cid, const float* __restrict__ clf_w,
    const float* __restrict__ clf_b, float* __restrict__ out) {
    const int c = blockIdx.x;
    const int t = threadIdx.x;
    __shared__ int cids[BATCH];
    __shared__ float red[256];
    for (int i = t; i < BATCH; i += 256) cids[i] = cid[i];
    __syncthreads();

    float lm = -1e30f;
    for (int b = t; b < BATCH; b += 256)
        if (cids[b] == c) lm = fmaxf(lm, logits[b]);
    red[t] = lm; __syncthreads();
    for (int s = 128; s > 0; s >>= 1) {
        if (t < s) red[t] = fmaxf(red[t], red[t + s]);
        __syncthreads();
    }
    float smax = red[0]; __syncthreads();

    float ls = 0.f;
    for (int b = t; b < BATCH; b += 256)
        if (cids[b] == c) ls += expf(logits[b] - smax);
    red[t] = ls; __syncthreads();
    for (int s = 128; s > 0; s >>= 1) {
        if (t < s) red[t] += red[t + s];
        __syncthreads();
    }
    float denom = red[0]; __syncthreads();
    float inv = (denom > 0.f) ? 1.f / denom : 0.f;

    const int h0 = t * 4;
    float g0 = 0.f, g1 = 0.f, g2 = 0.f, g3 = 0.f;
    for (int b = 0; b < BATCH; ++b) {
        if (cids[b] == c) {
            float wgt = expf(logits[b] - smax) * inv;
            float4 ev = *(const float4*)(emb + (size_t)b * HID + h0);
            g0 = fmaf(wgt, ev.x, g0);
            g1 = fmaf(wgt, ev.y, g1);
            g2 = fmaf(wgt, ev.z, g2);
            g3 = fmaf(wgt, ev.w, g3);
        }
    }
    float4 cw = *(const float4*)(clf_w + h0);
    float ca = g0 * cw.x + g1 * cw.y + g2 * cw.z + g3 * cw.w;
    red[t] = ca; __syncthreads();
    for (int s = 128; s > 0; s >>= 1) {
        if (t < s) red[t] += red[t + s];
        __syncthreads();
    }
    if (t == 0) out[c] = 1.f / (1.f + expf(-(red[0] + clf_b[0])));
}

// ---------------------------------------------------------------------------
extern "C" void kernel_launch(void* const* d_in, const int* in_sizes, int n_in,
                              void* d_out, int out_size, void* d_ws, size_t ws_size,
                              hipStream_t stream) {
    const float* data = (const float*)d_in[0];
    const int*   cid  = (const int*)d_in[1];
    const float* cw1 = (const float*)d_in[2],  * cb1 = (const float*)d_in[3];
    const float* cw2 = (const float*)d_in[4],  * cb2 = (const float*)d_in[5];
    const float* cw3 = (const float*)d_in[6],  * cb3 = (const float*)d_in[7];
    const float* cw4 = (const float*)d_in[8],  * cb4 = (const float*)d_in[9];
    const float* cw5 = (const float*)d_in[10], * cb5 = (const float*)d_in[11];
    const float* fcw = (const float*)d_in[12], * fcb = (const float*)d_in[13];
    const float* aw1 = (const float*)d_in[14], * ab1 = (const float*)d_in[15];
    const float* aw2 = (const float*)d_in[16], * ab2 = (const float*)d_in[17];
    const float* clw = (const float*)d_in[18], * clb = (const float*)d_in[19];
    float* out = (float*)d_out;

    // workspace (bytes), non-overlapping, ~71.9 MB
    char* wsb = (char*)d_ws;
    __bf16* x1  = (__bf16*)(wsb);              // 512*4096*8   bf16 = 33,554,432 B
    __bf16* x2  = (__bf16*)(wsb + 33554432);   // 512*1024*16  bf16 = 16,777,216 B
    __bf16* x3  = (__bf16*)(wsb + 50331648);   // 512*256*32   bf16 =  8,388,608 B
    __bf16* x4  = (__bf16*)(wsb + 58720256);   // 512*64*64    bf16 =  4,194,304 B
    __bf16* x5b = (__bf16*)(wsb + 62914560);   // 512*2048     bf16 =  2,097,152 B
    float*  emb = (float*) (wsb + 65011712);   // 512*1024     f32  =  2,097,152 B
    float*  lg  = (float*) (wsb + 67108864);   // 512 f32
    __bf16* wt2 = (__bf16*)(wsb + 67110912);   //   3,200 bf16
    __bf16* wt3 = (__bf16*)(wsb + 67117312);   //  12,800 bf16
    __bf16* wt4 = (__bf16*)(wsb + 67142912);   //  51,200 bf16
    __bf16* wt5 = (__bf16*)(wsb + 67245312);   // 204,800 bf16
    __bf16* wfc = (__bf16*)(wsb + 67654912);   // 2,097,152 bf16 = 4,194,304 B
    __bf16* wt1 = (__bf16*)(wsb + 71849216);   //   2,048 bf16

    wconv1_k<<<8, 256, 0, stream>>>(cw1, wt1);
    wconv_k<8,  16 ><<<(3200   + 255) / 256, 256, 0, stream>>>(cw2, wt2);
    wconv_k<16, 32 ><<<(12800  + 255) / 256, 256, 0, stream>>>(cw3, wt3);
    wconv_k<32, 64 ><<<(51200  + 255) / 256, 256, 0, stream>>>(cw4, wt4);
    wconv_k<64, 128><<<(204800 + 255) / 256, 256, 0, stream>>>(cw5, wt5);
    wfc_k<<<2097152 / 256, 256, 0, stream>>>(fcw, wfc);

    // 512 images x (128/4) row-blocks = 16384 blocks
    conv1_mfma_k<<<16384, 256, 0, stream>>>(data, wt1, cb1, x1);

    conv_mfma_k<8,  16,  64, 0><<<dim3(8192, 1), 256, 0, stream>>>(x1, wt2, cb2, x2);
    conv_mfma_k<16, 32,  32, 0><<<dim3(2048, 2), 256, 0, stream>>>(x2, wt3, cb3, x3);
    conv_mfma_k<32, 64,  16, 0><<<dim3(512,  4), 256, 0, stream>>>(x3, wt4, cb4, x4);
    conv_mfma_k<64, 128, 8,  1><<<dim3(128,  8), 256, 0, stream>>>(x4, wt5, cb5, x5b);

    fc_mfma_k<<<dim3(4, 64), 256, 0, stream>>>(x5b, wfc, fcb, emb);
    attention_k<<<BATCH, 128, 0, stream>>>(emb, aw1, ab1, aw2, ab2, lg);
    segment_k<<<NSEG, 256, 0, stream>>>(emb, lg, cid, clw, clb, out);
}

// Round 2
// 433.705 us; speedup vs baseline: 1.0759x; 1.0030x over previous
//
#include <hip/hip_runtime.h>
#include <hip/hip_bf16.h>
#include <math.h>

// Problem constants
#define BATCH 512
#define NSEG  64
#define HID   1024
#define ATT   128

typedef __attribute__((ext_vector_type(8))) __bf16 bf16x8;
typedef __attribute__((ext_vector_type(4))) __bf16 bf16x4;
typedef __attribute__((ext_vector_type(4))) float  f32x4;

// ---------------------------------------------------------------------------
// conv1 weight pre-convert: w[co][ci][kh][kw] (8,3,5,5) fp32 ->
// wt[k8][m16][j8] bf16 with k = tap*4 + ci (ci padded to 4), K=100 pad 128.
// ---------------------------------------------------------------------------
__global__ void wconv1_k(const float* __restrict__ w, __bf16* __restrict__ wt) {
    int t = blockIdx.x * 256 + threadIdx.x;   // n = 16*16*8 = 2048
    if (t >= 2048) return;
    int j = t & 7, m = (t >> 3) & 15, k8 = t >> 7;
    int k = k8 * 8 + j, tap = k >> 2, ci = k & 3;
    float v = 0.f;
    if (m < 8 && ci < 3 && tap < 25) v = w[(m * 3 + ci) * 25 + tap];
    wt[t] = (__bf16)v;
}

// ---------------------------------------------------------------------------
// conv1 via MFMA, 2D tile + zero-padded halo (verified round 1: 75 us).
// ---------------------------------------------------------------------------
__global__ __launch_bounds__(256) void conv1_mfma_k(
    const float* __restrict__ in, const __bf16* __restrict__ Wt,
    const float* __restrict__ bias, __bf16* __restrict__ out) {
    constexpr int W  = 128;
    constexpr int R  = 4;                  // output rows per block
    constexpr int RP = R + 4;              // padded rows (halo 2 each side)
    constexpr int WP = W + 4;              // padded cols
    constexpr int CSTR = R * W + 4;        // 516 f32

    __shared__ __align__(16) __bf16 xs[RP * WP * 4];   // 8448 B
    __shared__ float cs[8 * CSTR];                     // 16512 B

    const int tid = threadIdx.x;
    const int b   = blockIdx.x >> 5;            // 32 row-blocks per image
    const int y0  = (blockIdx.x & 31) * R;
    const float* inb = in + (size_t)b * 3 * 16384;

    if (tid < RP * 4) {
        int r = tid >> 2, s = tid & 3;
        int c = (s < 2) ? s : (128 + s);        // 0,1,130,131
        *(bf16x4*)(xs + (r * WP + c) * 4) = (bf16x4){};
    }
    {
        int r  = tid >> 5;                      // 0..7 padded row
        int g  = tid & 31;                      // col group, 4 cols
        int gy = y0 + r - 2;
        int c0 = g * 4;
        bf16x8 lo = {}, hi = {};
        if ((unsigned)gy < 128u) {
            const float* p = inb + (size_t)gy * 128 + c0;
            float4 a = *(const float4*)(p);
            float4 q = *(const float4*)(p + 16384);
            float4 c = *(const float4*)(p + 32768);
            lo[0] = (__bf16)a.x; lo[1] = (__bf16)q.x; lo[2] = (__bf16)c.x;
            lo[4] = (__bf16)a.y; lo[5] = (__bf16)q.y; lo[6] = (__bf16)c.y;
            hi[0] = (__bf16)a.z; hi[1] = (__bf16)q.z; hi[2] = (__bf16)c.z;
            hi[4] = (__bf16)a.w; hi[5] = (__bf16)q.w; hi[6] = (__bf16)c.w;
        }
        *(bf16x8*)(xs + (r * WP + c0 + 2) * 4)     = lo;
        *(bf16x8*)(xs + (r * WP + c0 + 2) * 4 + 8) = hi;
    }
    __syncthreads();

    const int lane = tid & 63, wave = tid >> 6;
    const int quad = lane >> 4, l15 = lane & 15;
    constexpr int F = 8;

    int pbase[F];
    f32x4 acc[F];
#pragma unroll
    for (int f = 0; f < F; ++f) {
        pbase[f] = ((wave + 2) * WP + f * 16 + l15 + 2) * 8;
        acc[f] = f32x4{0.f, 0.f, 0.f, 0.f};
    }
    const char* xsb = (const char*)xs;

#pragma unroll
    for (int kt = 0; kt < 4; ++kt) {
        int k8 = kt * 4 + quad;
        int tap0 = k8 * 2, tap1 = tap0 + 1;
        int t0 = tap0 < 25 ? tap0 : 0;
        int t1 = tap1 < 25 ? tap1 : 0;
        int s0 = ((t0 / 5 - 2) * WP + (t0 % 5 - 2)) * 8;
        int s1 = ((t1 / 5 - 2) * WP + (t1 % 5 - 2)) * 8;
        bf16x8 av = *(const bf16x8*)(Wt + ((size_t)k8 * 16 + l15) * 8);
#pragma unroll
        for (int f = 0; f < F; ++f) {
            bf16x4 b0 = *(const bf16x4*)(xsb + pbase[f] + s0);
            bf16x4 b1 = *(const bf16x4*)(xsb + pbase[f] + s1);
            bf16x8 bv = __builtin_shufflevector(b0, b1, 0, 1, 2, 3, 4, 5, 6, 7);
            acc[f] = __builtin_amdgcn_mfma_f32_16x16x32_bf16(av, bv, acc[f], 0, 0, 0);
        }
    }

#pragma unroll
    for (int f = 0; f < F; ++f) {
        int pl = wave * 128 + f * 16 + l15;
#pragma unroll
        for (int r = 0; r < 4; ++r) {
            int m = quad * 4 + r;
            if (m < 8) cs[m * CSTR + pl] = acc[f][r];
        }
    }
    __syncthreads();

    {
        int oi  = tid >> 1;                     // 0..127 pooled positions
        int cog = (tid & 1) * 4;                // 0 or 4
        int oy  = oi >> 6, ox = oi & 63;
        int pl0 = oy * 2 * 128 + ox * 2;
        float4 b4 = *(const float4*)(bias + cog);
        bf16x4 ov;
#pragma unroll
        for (int i = 0; i < 4; ++i) {
            int cr = cog + i;
            float v0 = cs[cr * CSTR + pl0],       v1 = cs[cr * CSTR + pl0 + 1];
            float v2 = cs[cr * CSTR + pl0 + 128], v3 = cs[cr * CSTR + pl0 + 129];
            float m = fmaxf(fmaxf(v0, v1), fmaxf(v2, v3)) + ((const float*)&b4)[i];
            ov[i] = (__bf16)fmaxf(m, 0.f);
        }
        size_t ob = ((size_t)b * 4096 + (size_t)(y0 / 2 + oy) * 64 + ox) * 8 + cog;
        *(bf16x4*)(out + ob) = ov;
    }
}

// ---------------------------------------------------------------------------
// Conv weight pre-convert: w[co][ci][kh][kw] fp32 -> wt[k/8][co][k%8] bf16,
// k = (kh*5+kw)*Ci + ci.
// ---------------------------------------------------------------------------
template<int Ci, int Co>
__global__ void wconv_k(const float* __restrict__ w, __bf16* __restrict__ wt) {
    const int n = 25 * Ci * Co;
    int t = blockIdx.x * 256 + threadIdx.x;
    if (t >= n) return;
    int j  = t & 7;
    int t2 = t >> 3;
    int co = t2 % Co;
    int k8 = t2 / Co;
    int k  = k8 * 8 + j;
    int tap = k / Ci, ci = k % Ci;
    int kh = tap / 5, kw = tap % 5;
    wt[t] = (__bf16)w[((co * Ci + ci) * 25) + kh * 5 + kw];
}

// ---------------------------------------------------------------------------
// FC weight pre-convert: fcw[o][k] fp32 (o<1024, k<2048) -> wt[k8][o][j] bf16.
// ---------------------------------------------------------------------------
__global__ void wfc_k(const float* __restrict__ w, __bf16* __restrict__ wt) {
    int t = blockIdx.x * 256 + threadIdx.x;   // n = 2,097,152
    int j  = t & 7;
    int t2 = t >> 3;
    int o  = t2 & 1023;
    int k8 = t2 >> 10;
    wt[t] = (__bf16)w[(size_t)o * 2048 + k8 * 8 + j];
}

// ---------------------------------------------------------------------------
// conv2..5: MFMA implicit-GEMM conv5x5(same) + bias + maxpool2 + relu,
// 2D tile + zero-padded halo (round 2 rewrite, no per-MFMA masking).
//   Ci,Co     channels (in NHWC-Ci, out NHWC-Co / flat)
//   H=W       spatial size; RB = rows per block; IMGS = images per block
//   OUTMODE   0 = NHWC bf16, 1 = flat [b][co*16+oy*4+ox] (conv5 -> FC)
// LDS per-position stride padded bank-coprime: 16/48/80/144 B for Ci=8..64.
// xs and cs are unioned (barrier between last xs read and cs write).
// ---------------------------------------------------------------------------
template<int Ci, int Co, int H, int RB, int IMGS, int OUTMODE>
__global__ __launch_bounds__(256) void conv2d_mfma_k(
    const __bf16* __restrict__ X, const __bf16* __restrict__ Wt,
    const float* __restrict__ bias, void* __restrict__ outp) {
    constexpr int W   = H;
    constexpr int PW  = W + 4;                    // padded cols
    constexpr int PR  = RB + 4;                   // padded rows
    constexpr int PIX = RB * W;                   // positions per image tile (pow2)
    constexpr int P   = IMGS * PIX;               // positions per block
    constexpr int SE  = Ci + (Ci >= 16 ? 8 : 0);  // LDS elems per position
    constexpr int SB  = SE * 2;                   // bytes (16/48/80/144)
    constexpr int K   = 25 * Ci;
    constexpr int KTF = K / 32;                   // full K-iterations
    constexpr int FW  = P / 64;                   // fragments per wave
    constexpr int PP  = P / 4;                    // pooled outputs per block
    constexpr int OW  = W / 2;
    constexpr int CSTR = P + 1;                   // odd: conflict-free cs
    constexpr int C8  = Ci / 8;
    constexpr int BPI = H / RB;                   // row-blocks per image

    constexpr int XS_B = IMGS * PR * PW * SB;
    constexpr int CS_B = 16 * CSTR * 4;
    constexpr int SM_B = XS_B > CS_B ? XS_B : CS_B;
    __shared__ __align__(16) char smem[SM_B];
    __bf16* xs = (__bf16*)smem;
    float*  cs = (float*)smem;

    const int tid = threadIdx.x;
    const int b0  = (blockIdx.x / BPI) * IMGS;
    const int y0  = (blockIdx.x % BPI) * RB;
    const int co0 = blockIdx.y * 16;

    // ---- stage padded tile(s); zeros at all out-of-image positions ----
    constexpr int NSLOT = IMGS * PR * PW * C8;
    for (int i = tid; i < NSLOT; i += 256) {
        int s   = i % C8;
        int t2  = i / C8;
        int pc  = t2 % PW;
        int t3  = t2 / PW;
        int pr  = t3 % PR;
        int img = t3 / PR;
        int gy  = y0 + pr - 2;
        int gx  = pc - 2;
        bf16x8 v = {};
        if ((unsigned)gy < (unsigned)H && (unsigned)gx < (unsigned)W)
            v = *(const bf16x8*)(X + (((size_t)(b0 + img) * H + gy) * W + gx) * Ci + s * 8);
        *(bf16x8*)((char*)xs + ((size_t)(img * PR + pr) * PW + pc) * SB + s * 16) = v;
    }
    __syncthreads();

    const int lane = tid & 63, wave = tid >> 6;
    const int quad = lane >> 4, l15 = lane & 15;

    int pbase[FW];
    f32x4 acc[FW];
#pragma unroll
    for (int f = 0; f < FW; ++f) {
        int pos = (wave * FW + f) * 16 + l15;
        int img = pos / PIX;                       // pow2
        int r   = (pos & (PIX - 1)) / W;           // pow2
        int c   = pos & (W - 1);
        pbase[f] = (img * PR + (r + 2)) * PW * SB + (c + 2) * SB;
        acc[f] = f32x4{0.f, 0.f, 0.f, 0.f};
    }
    const char* xsb = (const char*)smem;
    const bf16x8 BZ = {};

    auto body = [&](int kt, bool mask) {
        int k8  = kt * 4 + quad;
        int kk  = k8 * 8;
        int kok = 1;
        if (mask) { kok = kk < K; if (!kok) { k8 = 0; kk = 0; } }
        int tap = kk / Ci, cio = kk % Ci;          // pow2 -> shifts
        int dy  = tap / 5 - 2, dx = tap % 5 - 2;
        int shift = (dy * PW + dx) * SB + cio * 2;
        bf16x8 av = *(const bf16x8*)(Wt + ((size_t)k8 * Co + co0 + l15) * 8);
#pragma unroll
        for (int f = 0; f < FW; ++f) {
            bf16x8 bv = *(const bf16x8*)(xsb + pbase[f] + shift);
            if (mask && !kok) bv = BZ;
            acc[f] = __builtin_amdgcn_mfma_f32_16x16x32_bf16(av, bv, acc[f], 0, 0, 0);
        }
    };
#pragma unroll
    for (int kt = 0; kt < KTF; ++kt) body(kt, false);
    if constexpr (K % 32 != 0) body(KTF, true);

    __syncthreads();                               // xs reads done before cs write
#pragma unroll
    for (int f = 0; f < FW; ++f) {
        int pl = (wave * FW + f) * 16 + l15;
#pragma unroll
        for (int r = 0; r < 4; ++r) cs[(quad * 4 + r) * CSTR + pl] = acc[f][r];
    }
    __syncthreads();

    // ---- pool 2x2 + bias + relu ----
    constexpr int SLOTS = PP * 4;                  // (pooled pos) x 4 co-groups
    if (tid < SLOTS) {
        int opos = tid >> 2;
        int cog  = (tid & 3) * 4;
        constexpr int PPI = PIX / 4;               // pooled per image (pow2)
        int img  = opos / PPI;
        int rest = opos & (PPI - 1);
        int oyl  = rest / OW;
        int oxl  = rest & (OW - 1);
        int pl0  = img * PIX + (oyl * 2) * W + oxl * 2;
        int bb   = b0 + img;
        int oy   = (y0 >> 1) + oyl;
        float4 b4 = *(const float4*)(bias + co0 + cog);
        float mv[4];
#pragma unroll
        for (int i = 0; i < 4; ++i) {
            int cr = cog + i;
            float v0 = cs[cr * CSTR + pl0],     v1 = cs[cr * CSTR + pl0 + 1];
            float v2 = cs[cr * CSTR + pl0 + W], v3 = cs[cr * CSTR + pl0 + W + 1];
            float m = fmaxf(fmaxf(v0, v1), fmaxf(v2, v3)) + ((const float*)&b4)[i];
            mv[i] = fmaxf(m, 0.f);
        }
        if (OUTMODE == 1) {
#pragma unroll
            for (int i = 0; i < 4; ++i)
                ((__bf16*)outp)[(size_t)bb * 2048 + (co0 + cog + i) * 16 + oy * 4 + oxl] =
                    (__bf16)mv[i];
        } else {
            bf16x4 ov;
#pragma unroll
            for (int i = 0; i < 4; ++i) ov[i] = (__bf16)mv[i];
            *(bf16x4*)((__bf16*)outp +
                (((size_t)bb * (H / 2) + oy) * OW + oxl) * Co + co0 + cog) = ov;
        }
    }
}

// ---------------------------------------------------------------------------
// FC via MFMA (verified round 8).
// ---------------------------------------------------------------------------
__global__ __launch_bounds__(256) void fc_mfma_k(
    const __bf16* __restrict__ Xb, const __bf16* __restrict__ Wfc,
    const float* __restrict__ bias, float* __restrict__ emb) {
    const int tid  = threadIdx.x;
    const int lane = tid & 63, wave = tid >> 6;
    const int quad = lane >> 4, l15 = lane & 15;
    const int n0   = blockIdx.x * 128;
    const int co0  = blockIdx.y * 16;

    int n[2];
    f32x4 acc[2];
#pragma unroll
    for (int f = 0; f < 2; ++f) {
        n[f] = n0 + wave * 32 + f * 16 + l15;
        acc[f] = f32x4{0.f, 0.f, 0.f, 0.f};
    }

#pragma unroll 4
    for (int kt = 0; kt < 64; ++kt) {
        int k8 = kt * 4 + quad;
        bf16x8 av = *(const bf16x8*)(Wfc + ((size_t)k8 * 1024 + co0 + l15) * 8);
#pragma unroll
        for (int f = 0; f < 2; ++f) {
            bf16x8 bv = *(const bf16x8*)(Xb + (size_t)n[f] * 2048 + k8 * 8);
            acc[f] = __builtin_amdgcn_mfma_f32_16x16x32_bf16(av, bv, acc[f], 0, 0, 0);
        }
    }

    float4 b4 = *(const float4*)(bias + co0 + quad * 4);
#pragma unroll
    for (int f = 0; f < 2; ++f) {
        f32x4 v = acc[f];
        v[0] += b4.x; v[1] += b4.y; v[2] += b4.z; v[3] += b4.w;
        *(f32x4*)(emb + (size_t)n[f] * 1024 + co0 + quad * 4) = v;
    }
}

// ---------------------------------------------------------------------------
// Attention
// ---------------------------------------------------------------------------
__global__ __launch_bounds__(128) void attention_k(
    const float* __restrict__ emb, const float* __restrict__ w1,
    const float* __restrict__ b1, const float* __restrict__ w2,
    const float* __restrict__ b2, float* __restrict__ logits) {
    const int b = blockIdx.x;
    const int j = threadIdx.x;
    __shared__ float es[HID];
    for (int k = j; k < HID; k += 128) es[k] = emb[(size_t)b * HID + k];
    __syncthreads();

    float s = b1[j];
    const float* wr = w1 + (size_t)j * HID;
    for (int k = 0; k < HID; k += 4) {
        float4 wv = *(const float4*)(wr + k);
        float4 ev = *(const float4*)(es + k);
        s += wv.x * ev.x + wv.y * ev.y + wv.z * ev.z + wv.w * ev.w;
    }
    float v = tanhf(s) * w2[j];
#pragma unroll
    for (int off = 32; off > 0; off >>= 1) v += __shfl_down(v, off);
    __shared__ float wsum[2];
    if ((j & 63) == 0) wsum[j >> 6] = v;
    __syncthreads();
    if (j == 0) logits[b] = wsum[0] + wsum[1] + b2[0];
}

// ---------------------------------------------------------------------------
// Segment softmax + aggregation + classifier
// ---------------------------------------------------------------------------
__global__ __launch_bounds__(256) void segment_k(
    const float* __restrict__ emb, const float* __restrict__ logits,
    const int* __restrict__ cid, const float* __restrict__ clf_w,
    const float* __restrict__ clf_b, float* __restrict__ out) {
    const int c = blockIdx.x;
    const int t = threadIdx.x;
    __shared__ int cids[BATCH];
    __shared__ float red[256];
    for (int i = t; i < BATCH; i += 256) cids[i] = cid[i];
    __syncthreads();

    float lm = -1e30f;
    for (int b = t; b < BATCH; b += 256)
        if (cids[b] == c) lm = fmaxf(lm, logits[b]);
    red[t] = lm; __syncthreads();
    for (int s = 128; s > 0; s >>= 1) {
        if (t < s) red[t] = fmaxf(red[t], red[t + s]);
        __syncthreads();
    }
    float smax = red[0]; __syncthreads();

    float ls = 0.f;
    for (int b = t; b < BATCH; b += 256)
        if (cids[b] == c) ls += expf(logits[b] - smax);
    red[t] = ls; __syncthreads();
    for (int s = 128; s > 0; s >>= 1) {
        if (t < s) red[t] += red[t + s];
        __syncthreads();
    }
    float denom = red[0]; __syncthreads();
    float inv = (denom > 0.f) ? 1.f / denom : 0.f;

    const int h0 = t * 4;
    float g0 = 0.f, g1 = 0.f, g2 = 0.f, g3 = 0.f;
    for (int b = 0; b < BATCH; ++b) {
        if (cids[b] == c) {
            float wgt = expf(logits[b] - smax) * inv;
            float4 ev = *(const float4*)(emb + (size_t)b * HID + h0);
            g0 = fmaf(wgt, ev.x, g0);
            g1 = fmaf(wgt, ev.y, g1);
            g2 = fmaf(wgt, ev.z, g2);
            g3 = fmaf(wgt, ev.w, g3);
        }
    }
    float4 cw = *(const float4*)(clf_w + h0);
    float ca = g0 * cw.x + g1 * cw.y + g2 * cw.z + g3 * cw.w;
    red[t] = ca; __syncthreads();
    for (int s = 128; s > 0; s >>= 1) {
        if (t < s) red[t] += red[t + s];
        __syncthreads();
    }
    if (t == 0) out[c] = 1.f / (1.f + expf(-(red[0] + clf_b[0])));
}

// ---------------------------------------------------------------------------
extern "C" void kernel_launch(void* const* d_in, const int* in_sizes, int n_in,
                              void* d_out, int out_size, void* d_ws, size_t ws_size,
                              hipStream_t stream) {
    const float* data = (const float*)d_in[0];
    const int*   cid  = (const int*)d_in[1];
    const float* cw1 = (const float*)d_in[2],  * cb1 = (const float*)d_in[3];
    const float* cw2 = (const float*)d_in[4],  * cb2 = (const float*)d_in[5];
    const float* cw3 = (const float*)d_in[6],  * cb3 = (const float*)d_in[7];
    const float* cw4 = (const float*)d_in[8],  * cb4 = (const float*)d_in[9];
    const float* cw5 = (const float*)d_in[10], * cb5 = (const float*)d_in[11];
    const float* fcw = (const float*)d_in[12], * fcb = (const float*)d_in[13];
    const float* aw1 = (const float*)d_in[14], * ab1 = (const float*)d_in[15];
    const float* aw2 = (const float*)d_in[16], * ab2 = (const float*)d_in[17];
    const float* clw = (const float*)d_in[18], * clb = (const float*)d_in[19];
    float* out = (float*)d_out;

    // workspace (bytes), non-overlapping, ~71.9 MB
    char* wsb = (char*)d_ws;
    __bf16* x1  = (__bf16*)(wsb);              // 512*4096*8   bf16 = 33,554,432 B
    __bf16* x2  = (__bf16*)(wsb + 33554432);   // 512*1024*16  bf16 = 16,777,216 B
    __bf16* x3  = (__bf16*)(wsb + 50331648);   // 512*256*32   bf16 =  8,388,608 B
    __bf16* x4  = (__bf16*)(wsb + 58720256);   // 512*64*64    bf16 =  4,194,304 B
    __bf16* x5b = (__bf16*)(wsb + 62914560);   // 512*2048     bf16 =  2,097,152 B
    float*  emb = (float*) (wsb + 65011712);   // 512*1024     f32  =  2,097,152 B
    float*  lg  = (float*) (wsb + 67108864);   // 512 f32
    __bf16* wt2 = (__bf16*)(wsb + 67110912);   //   3,200 bf16
    __bf16* wt3 = (__bf16*)(wsb + 67117312);   //  12,800 bf16
    __bf16* wt4 = (__bf16*)(wsb + 67142912);   //  51,200 bf16
    __bf16* wt5 = (__bf16*)(wsb + 67245312);   // 204,800 bf16
    __bf16* wfc = (__bf16*)(wsb + 67654912);   // 2,097,152 bf16 = 4,194,304 B
    __bf16* wt1 = (__bf16*)(wsb + 71849216);   //   2,048 bf16

    wconv1_k<<<8, 256, 0, stream>>>(cw1, wt1);
    wconv_k<8,  16 ><<<(3200   + 255) / 256, 256, 0, stream>>>(cw2, wt2);
    wconv_k<16, 32 ><<<(12800  + 255) / 256, 256, 0, stream>>>(cw3, wt3);
    wconv_k<32, 64 ><<<(51200  + 255) / 256, 256, 0, stream>>>(cw4, wt4);
    wconv_k<64, 128><<<(204800 + 255) / 256, 256, 0, stream>>>(cw5, wt5);
    wfc_k<<<2097152 / 256, 256, 0, stream>>>(fcw, wfc);

    // conv1: 512 images x 32 row-blocks
    conv1_mfma_k<<<16384, 256, 0, stream>>>(data, wt1, cb1, x1);

    // conv2..5: 2D-tile zero-padded-halo template
    conv2d_mfma_k<8,  16,  64, 4,  1, 0><<<dim3(512 * 16, 1), 256, 0, stream>>>(x1, wt2, cb2, x2);
    conv2d_mfma_k<16, 32,  32, 8,  1, 0><<<dim3(512 * 4,  2), 256, 0, stream>>>(x2, wt3, cb3, x3);
    conv2d_mfma_k<32, 64,  16, 16, 1, 0><<<dim3(512,      4), 256, 0, stream>>>(x3, wt4, cb4, x4);
    conv2d_mfma_k<64, 128, 8,  8,  2, 1><<<dim3(256,      8), 256, 0, stream>>>(x4, wt5, cb5, x5b);

    fc_mfma_k<<<dim3(4, 64), 256, 0, stream>>>(x5b, wfc, fcb, emb);
    attention_k<<<BATCH, 128, 0, stream>>>(emb, aw1, ab1, aw2, ab2, lg);
    segment_k<<<NSEG, 256, 0, stream>>>(emb, lg, cid, clw, clb, out);
}